// Round 4
// baseline (319.120 us; speedup 1.0000x reference)
//
#include <hip/hip_runtime.h>
#include <stdint.h>
#include <stddef.h>

// ---------------- types ----------------
typedef __bf16 bf16_t;
typedef bf16_t bf16x4v __attribute__((ext_vector_type(4)));
typedef bf16_t bf16x8v __attribute__((ext_vector_type(8)));
typedef float  f32x4   __attribute__((ext_vector_type(4)));

#define NBATCH 8
#define SEQ    2048
#define DIM    512
#define SP     2052   // padded seq (mult of 12)
#define NB2    1026
#define NB3    684
#define NB4    513
#define NL     512    // output rows per batch (SEQ/4)
#define NBLK   512    // persistent grid (2 blocks/CU guaranteed)

static __device__ __forceinline__ f32x4 ldbf4(const bf16_t* p) {
  bf16x4v v = *(const bf16x4v*)p;
  f32x4 r;
  r.x = (float)v[0]; r.y = (float)v[1]; r.z = (float)v[2]; r.w = (float)v[3];
  return r;
}
static __device__ __forceinline__ void stbf4(bf16_t* p, f32x4 v) {
  bf16x4v o;
  o[0] = (bf16_t)v.x; o[1] = (bf16_t)v.y; o[2] = (bf16_t)v.z; o[3] = (bf16_t)v.w;
  *(bf16x4v*)p = o;
}

static __device__ __forceinline__ void gload_lds16(const void* g, void* l) {
  __builtin_amdgcn_global_load_lds(
      (const __attribute__((address_space(1))) void*)g,
      (__attribute__((address_space(3))) void*)l, 16, 0, 0);
}

// device-scope grid barrier (monotonic ticket; all NBLK blocks co-resident).
// __threadfence() on gfx950 emits agent-scope release (L2 writeback) so
// cross-XCD readers see data after the barrier.
static __device__ __forceinline__ void gsync(int* bar, int target) {
  __syncthreads();
  if (threadIdx.x == 0) {
    __threadfence();
    atomicAdd(bar, 1);
    while (atomicAdd(bar, 0) < target) __builtin_amdgcn_s_sleep(2);
    __threadfence();
  }
  __syncthreads();
}

// ---------------- the mega-kernel ----------------
#define BM 64
#define BN 128
#define BK 32

__global__ __launch_bounds__(256, 2) void mega(
    const int* __restrict__ x, const void* __restrict__ mraw,
    const float* __restrict__ emb, const float* __restrict__ dww,
    const float* __restrict__ dwb, const float* __restrict__ pw,
    const float* __restrict__ pwb, const float* __restrict__ sw,
    const float* __restrict__ sbp,
    bf16_t* __restrict__ A, bf16_t* __restrict__ H, bf16_t* __restrict__ Wt,
    bf16_t* __restrict__ R2, bf16_t* __restrict__ R3, bf16_t* __restrict__ R4,
    float* __restrict__ mask01, float* __restrict__ P,
    float* __restrict__ out, float* __restrict__ omask, int* bar) {
  __shared__ __align__(16) char smem[33024];
  const int bid = blockIdx.x, t = threadIdx.x;

  // ================= Phase 1: Wt transpose + mask + depthwise A ========
  if (bid < 256) {
    // LDS-tiled transpose: pw (K,N) f32 -> Wt (N,K) bf16, 32x32 tiles
    float (*T)[33] = (float(*)[33])smem;
    int ti = bid >> 4, tj = bid & 15;
    int r = t >> 3, c0 = (t & 7) * 4;
    f32x4 v = *(const f32x4*)(pw + (size_t)(ti * 32 + r) * DIM + tj * 32 + c0);
    T[c0 + 0][r] = v.x; T[c0 + 1][r] = v.y;
    T[c0 + 2][r] = v.z; T[c0 + 3][r] = v.w;
    __syncthreads();
    bf16x4v o;
    o[0] = (bf16_t)T[r][c0 + 0]; o[1] = (bf16_t)T[r][c0 + 1];
    o[2] = (bf16_t)T[r][c0 + 2]; o[3] = (bf16_t)T[r][c0 + 3];
    *(bf16x4v*)(Wt + (size_t)(tj * 32 + r) * DIM + ti * 32 + c0) = o;
  } else if (bid < 321) {
    int idx = (bid - 256) * 256 + t;
    if (idx < NBATCH * SP) {
      int b = idx / SP, s = idx - b * SP;
      const unsigned char* mb = (const unsigned char*)mraw;
      int u8 = 0;
#pragma unroll
      for (int i = 0; i < 64; i++)
        if ((i & 3) != 0 && mb[i] != 0) u8 = 1;
      float v = 0.f;
      if (s < SEQ) {
        int mi = b * SEQ + s;
        int nz = u8 ? (mb[mi] != 0) : (((const int*)mraw)[mi] != 0);
        v = nz ? 1.f : 0.f;
      }
      mask01[idx] = v;
    }
  }
  // depthwise conv: all blocks, 16 row-pairs each
  {
    int d0 = (t & 127) * 4;
    int rsel = t >> 7;
#pragma unroll 4
    for (int i = 0; i < 16; i++) {
      int row = (bid * 16 + i) * 2 + rsel;
      int b = row >> 11, s = row & 2047;
      f32x4 acc = *(const f32x4*)(dwb + d0);
#pragma unroll
      for (int tt = 0; tt < 4; tt++) {
        int sp = s + tt;
        if (sp < SEQ) {
          int v = x[b * SEQ + sp];
          f32x4 e = *(const f32x4*)(emb + (size_t)v * DIM + d0);
          f32x4 w = *(const f32x4*)(dww + tt * DIM + d0);
          acc += e * w;
        }
      }
      stbf4(A + (size_t)row * DIM + d0, acc);
    }
  }
  gsync(bar, NBLK);

  // ================= Phase 2: GEMM H = A @ Wt^T + pw_b =================
  {
    bf16_t* As = (bf16_t*)smem;             // 4 KB
    bf16_t* Bs = As + BM * BK;              // 8 KB
    const int lane = t & 63, wave = t >> 6;
    const int wm = (wave & 1) * 32, wn = (wave >> 1) * 64;
    const int mloc = lane & 15, quad = lane >> 4;
    char* asd  = (char*)As + t * 16;
    char* bsd1 = (char*)Bs + t * 16;
    char* bsd2 = (char*)Bs + (t + 256) * 16;
    const int ar = t >> 2, ak = (t & 3) * 8;
    const int br2 = (t + 256) >> 2;
#pragma unroll 1
    for (int half = 0; half < 2; half++) {
      int tile = bid + half * 512;          // 0..1023
      int xcd = tile & 7, loc = tile >> 3;
      int mt = xcd * 32 + (loc >> 2), nt = loc & 3;
      int m0 = mt * BM, n0 = nt * BN;
      f32x4 acc[2][4] = {};
      for (int k0 = 0; k0 < 512; k0 += BK) {
        gload_lds16(A + (size_t)(m0 + ar) * DIM + k0 + ak, asd);
        gload_lds16(Wt + (size_t)(n0 + ar) * DIM + k0 + ak, bsd1);
        gload_lds16(Wt + (size_t)(n0 + br2) * DIM + k0 + ak, bsd2);
        __syncthreads();
        bf16x8v af[2], bfr[4];
#pragma unroll
        for (int i = 0; i < 2; i++)
          af[i] = *(const bf16x8v*)&As[(wm + i * 16 + mloc) * BK + quad * 8];
#pragma unroll
        for (int i = 0; i < 4; i++)
          bfr[i] = *(const bf16x8v*)&Bs[(wn + i * 16 + mloc) * BK + quad * 8];
#pragma unroll
        for (int mi = 0; mi < 2; mi++)
#pragma unroll
          for (int ni = 0; ni < 4; ni++)
            acc[mi][ni] = __builtin_amdgcn_mfma_f32_16x16x32_bf16(
                af[mi], bfr[ni], acc[mi][ni], 0, 0, 0);
        __syncthreads();
      }
#pragma unroll
      for (int ni = 0; ni < 4; ni++) {
        int col = n0 + wn + ni * 16 + mloc;
        float bv = pwb[col];
#pragma unroll
        for (int mi = 0; mi < 2; mi++) {
          int rbase = m0 + wm + mi * 16 + quad * 4;
#pragma unroll
          for (int r = 0; r < 4; r++)
            H[(size_t)(rbase + r) * DIM + col] = (bf16_t)(acc[mi][ni][r] + bv);
        }
      }
    }
  }
  gsync(bar, 2 * NBLK);

  // ================= Phase 3: level means + block-score softmax -> P ===
  {
    float* hsw = (float*)smem;              // [2 halves][2 waves][12]
    const int h = t >> 7, t1 = t & 127, wv = (t >> 6) & 1, lane = t & 63;
    const float sb = sbp[0];
#pragma unroll 1
    for (int pass = 0; pass < 2; pass++) {
      int unit = pass * 1024 + bid * 2 + h;
      bool act = unit < 1368;
      int uu = act ? unit : 0;
      int b = uu / 171, c = uu - b * 171;
      int s0 = c * 12, d0 = t1 * 4;
      f32x4 hh[12];
      float ms[12], p[12];
      f32x4 swv = *(const f32x4*)(sw + d0);
#pragma unroll
      for (int i = 0; i < 12; i++) {
        int s = s0 + i;
        ms[i] = mask01[b * SP + s];
        if (s < SEQ) {
          hh[i] = ldbf4(H + ((size_t)b * SEQ + s) * DIM + d0);
        } else {
          hh[i].x = hh[i].y = hh[i].z = hh[i].w = 0.f;
        }
        p[i] = hh[i].x * swv.x + hh[i].y * swv.y + hh[i].z * swv.z +
               hh[i].w * swv.w;
      }
      if (act) {
#pragma unroll
        for (int j = 0; j < 6; j++) {
          int i0 = 2 * j;
          float cc = ms[i0] + ms[i0 + 1];
          f32x4 sm = hh[i0] * ms[i0] + hh[i0 + 1] * ms[i0 + 1];
          float sc = cc > 0.f ? 1.f / cc : 0.f;
          stbf4(R2 + ((size_t)b * NB2 + (c * 6 + j)) * DIM + d0, sm * sc);
        }
#pragma unroll
        for (int j = 0; j < 4; j++) {
          int i0 = 3 * j;
          float cc = ms[i0] + ms[i0 + 1] + ms[i0 + 2];
          f32x4 sm = hh[i0] * ms[i0] + hh[i0 + 1] * ms[i0 + 1] +
                     hh[i0 + 2] * ms[i0 + 2];
          float sc = cc > 0.f ? 1.f / cc : 0.f;
          stbf4(R3 + ((size_t)b * NB3 + (c * 4 + j)) * DIM + d0, sm * sc);
        }
#pragma unroll
        for (int j = 0; j < 3; j++) {
          int i0 = 4 * j;
          float cc = ms[i0] + ms[i0 + 1] + ms[i0 + 2] + ms[i0 + 3];
          f32x4 sm = hh[i0] * ms[i0] + hh[i0 + 1] * ms[i0 + 1] +
                     hh[i0 + 2] * ms[i0 + 2] + hh[i0 + 3] * ms[i0 + 3];
          float sc = cc > 0.f ? 1.f / cc : 0.f;
          stbf4(R4 + ((size_t)b * NB4 + (c * 3 + j)) * DIM + d0, sm * sc);
        }
      }
#pragma unroll
      for (int off = 32; off > 0; off >>= 1)
#pragma unroll
        for (int i = 0; i < 12; i++) p[i] += __shfl_down(p[i], off);
      if (lane == 0)
#pragma unroll
        for (int i = 0; i < 12; i++) hsw[(h * 2 + wv) * 12 + i] = p[i];
      __syncthreads();
#define HSUM(i) (hsw[(h * 2) * 12 + (i)] + hsw[(h * 2 + 1) * 12 + (i)])
      if (act && t1 < 12) {
        int i = t1;
        float m1 = ms[i];
        float v1 = HSUM(i) * m1 + sb;
        int i2 = i & ~1;
        float cc2 = ms[i2] + ms[i2 + 1];
        float s2 = HSUM(i2) * ms[i2] + HSUM(i2 + 1) * ms[i2 + 1];
        float v2 = (cc2 > 0.f ? s2 / cc2 : 0.f) + sb;
        int i3 = (i >= 9) ? 9 : (i >= 6) ? 6 : (i >= 3) ? 3 : 0;
        float cc3 = ms[i3] + ms[i3 + 1] + ms[i3 + 2];
        float s3 = HSUM(i3) * ms[i3] + HSUM(i3 + 1) * ms[i3 + 1] +
                   HSUM(i3 + 2) * ms[i3 + 2];
        float v3 = (cc3 > 0.f ? s3 / cc3 : 0.f) + sb;
        int i4 = i & ~3;
        float cc4 = ms[i4] + ms[i4 + 1] + ms[i4 + 2] + ms[i4 + 3];
        float s4 = HSUM(i4) * ms[i4] + HSUM(i4 + 1) * ms[i4 + 1] +
                   HSUM(i4 + 2) * ms[i4 + 2] + HSUM(i4 + 3) * ms[i4 + 3];
        float v4 = (cc4 > 0.f ? s4 / cc4 : 0.f) + sb;
        const float NEG = -3.0e38f;
        float a1 = m1 > 0.f ? v1 : NEG, a2 = cc2 > 0.f ? v2 : NEG;
        float a3 = cc3 > 0.f ? v3 : NEG, a4 = cc4 > 0.f ? v4 : NEG;
        float mx = fmaxf(fmaxf(a1, a2), fmaxf(a3, a4));
        f32x4 o;
        if (mx <= NEG) {
          o.x = o.y = o.z = o.w = 0.25f;
        } else {
          float e1 = m1 > 0.f ? __expf(v1 - mx) : 0.f;
          float e2 = cc2 > 0.f ? __expf(v2 - mx) : 0.f;
          float e3 = cc3 > 0.f ? __expf(v3 - mx) : 0.f;
          float e4 = cc4 > 0.f ? __expf(v4 - mx) : 0.f;
          float inv = 1.f / (e1 + e2 + e3 + e4);
          o.x = e1 * inv; o.y = e2 * inv; o.z = e3 * inv; o.w = e4 * inv;
        }
        *(f32x4*)(P + ((size_t)b * SP + s0 + i) * 4) = o;
      }
#undef HSUM
      __syncthreads();
    }
  }
  gsync(bar, 3 * NBLK);

  // ====== Phase 4: fused seq attention + output (stage all P[b] in LDS) =
  {
    f32x4* Qs = (f32x4*)smem;                    // 2052 * 16B = 32832
    float* nmp  = (float*)(smem + 32832);
    f32x4* wshl = (f32x4*)(smem + 32848);        // 4
    float* mshl = (float*)(smem + 32912);        // 4
    const int b = bid >> 6, lbase = (bid & 63) * 8;
    if (t == 0) *nmp = 0.f;
    __syncthreads();
    // stage P rows, zero masked rows (exp(0)=1 corrected via den -= nmask)
    for (int j = t; j < SP; j += 256) {
      f32x4 q = *(const f32x4*)(P + ((size_t)b * SP + j) * 4);
      float mf = mask01[b * SP + j];
      if (mf == 0.f) {
        q.x = q.y = q.z = q.w = 0.f;
        atomicAdd(nmp, 1.f);
      }
      Qs[j] = q;
    }
    __syncthreads();
    const float nmv = *nmp;
    const int w = t >> 6, lane = t & 63;
#pragma unroll 1
    for (int li = 0; li < 8; li++) {
      int l = lbase + li;
      int s = l * 4 + w;                    // wave w handles row s
      f32x4 qi = Qs[s];
      f32x4 acc; acc.x = acc.y = acc.z = acc.w = 0.f;
      float den = 0.f;
      for (int j = lane; j < SP; j += 64) {
        f32x4 pj = Qs[j];
        float e = __expf(qi.x * pj.x + qi.y * pj.y + qi.z * pj.z +
                         qi.w * pj.w);
        den += e;
        acc += e * pj;
      }
#pragma unroll
      for (int off = 32; off > 0; off >>= 1) {
        acc.x += __shfl_down(acc.x, off);
        acc.y += __shfl_down(acc.y, off);
        acc.z += __shfl_down(acc.z, off);
        acc.w += __shfl_down(acc.w, off);
        den   += __shfl_down(den, off);
      }
      if (lane == 0) {
        den -= nmv;
        float inv = den > 0.f ? 1.f / den : 0.f;
        f32x4 wv4; wv4.x = acc.x * inv; wv4.y = acc.y * inv;
        wv4.z = acc.z * inv; wv4.w = acc.w * inv;
        wshl[w] = wv4;
        mshl[w] = mask01[b * SP + s];
      }
      __syncthreads();
      if (t < 128) {
        int d0 = t * 4;
        f32x4 o; o.x = o.y = o.z = o.w = 0.f;
        float cnt = 0.f;
#pragma unroll
        for (int si = 0; si < 4; si++) {
          int ss = l * 4 + si;
          float m = mshl[si];
          f32x4 wv4 = wshl[si];
          f32x4 r1 = ldbf4(H + ((size_t)b * SEQ + ss) * DIM + d0);
          f32x4 r2 = ldbf4(R2 + ((size_t)b * NB2 + (ss >> 1)) * DIM + d0);
          f32x4 r3 = ldbf4(R3 + ((size_t)b * NB3 + (ss / 3)) * DIM + d0);
          f32x4 r4 = ldbf4(R4 + ((size_t)b * NB4 + (ss >> 2)) * DIM + d0);
          o += m * (wv4.x * r1 + wv4.y * r2 + wv4.z * r3 + wv4.w * r4);
          cnt += m;
        }
        float inv = cnt > 0.f ? 1.f / cnt : 0.f;
        o *= inv;
        *(f32x4*)(out + ((size_t)b * NL + l) * DIM + d0) = o;
        if (t == 0) omask[b * NL + l] = cnt > 0.f ? 1.f : 0.f;
      }
      __syncthreads();
    }
  }
}

// ---------------- launch ----------------
extern "C" void kernel_launch(void* const* d_in, const int* in_sizes, int n_in,
                              void* d_out, int out_size, void* d_ws, size_t ws_size,
                              hipStream_t stream) {
  const int*   x    = (const int*)d_in[0];
  const void*  mraw = d_in[1];
  const float* emb  = (const float*)d_in[2];
  const float* dww  = (const float*)d_in[3];
  const float* dwb  = (const float*)d_in[4];
  const float* pw   = (const float*)d_in[5];
  const float* pwb  = (const float*)d_in[6];
  const float* sw   = (const float*)d_in[7];
  const float* sb   = (const float*)d_in[8];

  char* ws = (char*)d_ws;
  size_t off = 0;
  auto alloc = [&](size_t bytes) {
    size_t o = off;
    off = (off + bytes + 255) & ~(size_t)255;
    return o;
  };
  int*   bar   = (int*)(ws + alloc(256));
  bf16_t* A    = (bf16_t*)(ws + alloc((size_t)NBATCH * SEQ * DIM * 2));
  bf16_t* H    = (bf16_t*)(ws + alloc((size_t)NBATCH * SEQ * DIM * 2));
  bf16_t* Wt   = (bf16_t*)(ws + alloc((size_t)DIM * DIM * 2));
  bf16_t* R2   = (bf16_t*)(ws + alloc((size_t)NBATCH * NB2 * DIM * 2));
  bf16_t* R3   = (bf16_t*)(ws + alloc((size_t)NBATCH * NB3 * DIM * 2));
  bf16_t* R4   = (bf16_t*)(ws + alloc((size_t)NBATCH * NB4 * DIM * 2));
  float* mask01 = (float*)(ws + alloc((size_t)NBATCH * SP * 4));
  float* P     = (float*)(ws + alloc((size_t)NBATCH * SP * 4 * 4));

  float* out   = (float*)d_out;
  float* omask = out + (size_t)NBATCH * NL * DIM;

  hipMemsetAsync(bar, 0, 256, stream);
  mega<<<NBLK, 256, 0, stream>>>(x, mraw, emb, dww, dwb, pw, pwb, sw, sb,
                                 A, H, Wt, R2, R3, R4, mask01, P,
                                 out, omask, bar);
}

// Round 7
// 153.136 us; speedup vs baseline: 2.0839x; 2.0839x over previous
//
#include <hip/hip_runtime.h>
#include <stdint.h>
#include <stddef.h>

// ---------------- types ----------------
typedef __bf16 bf16_t;
typedef bf16_t bf16x4v __attribute__((ext_vector_type(4)));
typedef bf16_t bf16x8v __attribute__((ext_vector_type(8)));
typedef float  f32x4   __attribute__((ext_vector_type(4)));

#define NBATCH 8
#define SEQ    2048
#define DIM    512
#define SP     2052   // padded seq (mult of 12)
#define NB2    1026
#define NB3    684
#define NB4    513
#define NL     512    // output rows per batch (SEQ/4)

static __device__ __forceinline__ f32x4 ldbf4(const bf16_t* p) {
  bf16x4v v = *(const bf16x4v*)p;
  f32x4 r;
  r.x = (float)v[0]; r.y = (float)v[1]; r.z = (float)v[2]; r.w = (float)v[3];
  return r;
}
static __device__ __forceinline__ void stbf4(bf16_t* p, f32x4 v) {
  bf16x4v o;
  o[0] = (bf16_t)v.x; o[1] = (bf16_t)v.y; o[2] = (bf16_t)v.z; o[3] = (bf16_t)v.w;
  *(bf16x4v*)p = o;
}

static __device__ __forceinline__ void gload_lds16(const void* g, void* l) {
  __builtin_amdgcn_global_load_lds(
      (const __attribute__((address_space(1))) void*)g,
      (__attribute__((address_space(3))) void*)l, 16, 0, 0);
}

// ---------------- kA: fused Wt transpose + mask normalize + depthwise A --
#define GA_WT   256                        // 16x16 tiles of 32x32
#define GA_MASK 65                         // ceil(8*2052 / 256)
#define GA_A    (NBATCH * SEQ / 2)         // 8192 blocks, 2 rows each
__global__ __launch_bounds__(256) void kA_prep(
    const float* __restrict__ pw, bf16_t* __restrict__ Wt,
    const void* __restrict__ mraw, float* __restrict__ mask01,
    const int* __restrict__ x, const float* __restrict__ emb,
    const float* __restrict__ dww, const float* __restrict__ dwb,
    bf16_t* __restrict__ A) {
  const int bx = blockIdx.x, t = threadIdx.x;
  if (bx < GA_WT) {
    // LDS-tiled transpose: pw (K,N) f32 -> Wt (N,K) bf16, 32x32 tiles
    __shared__ float T[32][33];
    int ti = bx >> 4, tj = bx & 15;        // tile k-row, tile n-col
    int r = t >> 3, c0 = (t & 7) * 4;
    f32x4 v = *(const f32x4*)(pw + (size_t)(ti * 32 + r) * DIM + tj * 32 + c0);
    T[c0 + 0][r] = v.x; T[c0 + 1][r] = v.y;
    T[c0 + 2][r] = v.z; T[c0 + 3][r] = v.w;
    __syncthreads();
    bf16x4v o;
    o[0] = (bf16_t)T[r][c0 + 0]; o[1] = (bf16_t)T[r][c0 + 1];
    o[2] = (bf16_t)T[r][c0 + 2]; o[3] = (bf16_t)T[r][c0 + 3];
    *(bf16x4v*)(Wt + (size_t)(tj * 32 + r) * DIM + ti * 32 + c0) = o;
    return;
  }
  if (bx < GA_WT + GA_MASK) {
    int idx = (bx - GA_WT) * 256 + t;
    if (idx >= NBATCH * SP) return;
    int b = idx / SP, s = idx - b * SP;
    const unsigned char* mb = (const unsigned char*)mraw;
    int u8 = 0;
#pragma unroll
    for (int i = 0; i < 64; i++)
      if ((i & 3) != 0 && mb[i] != 0) u8 = 1;
    float v = 0.f;
    if (s < SEQ) {
      int mi = b * SEQ + s;
      int nz = u8 ? (mb[mi] != 0) : (((const int*)mraw)[mi] != 0);
      v = nz ? 1.f : 0.f;
    }
    mask01[idx] = v;
    return;
  }
  // depthwise conv: 2 rows per block
  int rp = bx - (GA_WT + GA_MASK);
  int row = rp * 2 + (t >> 7);             // 0..16383
  int b = row >> 11, s = row & 2047;
  int d0 = (t & 127) * 4;
  f32x4 acc = *(const f32x4*)(dwb + d0);
#pragma unroll
  for (int tt = 0; tt < 4; tt++) {
    int sp = s + tt;
    if (sp < SEQ) {
      int v = x[b * SEQ + sp];
      f32x4 e = *(const f32x4*)(emb + (size_t)v * DIM + d0);
      f32x4 w = *(const f32x4*)(dww + tt * DIM + d0);
      acc += e * w;
    }
  }
  stbf4(A + (size_t)row * DIM + d0, acc);
}

// ---------------- k2: H = A @ Wt^T + pw_b  (bf16 MFMA) ------------------
#define BM 64
#define BN 128
#define BK 32
__global__ __launch_bounds__(256) void k2_gemm(
    const bf16_t* __restrict__ A, const bf16_t* __restrict__ Bt,
    const float* __restrict__ bias, bf16_t* __restrict__ H) {
  __shared__ __align__(16) bf16_t As[BM * BK];   // 4 KB
  __shared__ __align__(16) bf16_t Bs[BN * BK];   // 8 KB
  const int t = threadIdx.x;
  const int bid = blockIdx.x;
  const int xcd = bid & 7, loc = bid >> 3;       // loc 0..127
  const int mt = xcd * 32 + (loc >> 2);          // 0..255
  const int nt = loc & 3;                        // 0..3
  const int m0 = mt * BM, n0 = nt * BN;
  const int lane = t & 63, wave = t >> 6;
  const int wm = (wave & 1) * 32, wn = (wave >> 1) * 64;
  const int mloc = lane & 15, quad = lane >> 4;

  f32x4 acc[2][4] = {};

  char* asd  = (char*)As + t * 16;
  char* bsd1 = (char*)Bs + t * 16;
  char* bsd2 = (char*)Bs + (t + 256) * 16;
  const int ar = t >> 2, ak = (t & 3) * 8;
  const int br2 = (t + 256) >> 2;

  for (int k0 = 0; k0 < 512; k0 += BK) {
    gload_lds16(A + (size_t)(m0 + ar) * DIM + k0 + ak, asd);
    gload_lds16(Bt + (size_t)(n0 + ar) * DIM + k0 + ak, bsd1);
    gload_lds16(Bt + (size_t)(n0 + br2) * DIM + k0 + ak, bsd2);
    __syncthreads();
    bf16x8v af[2], bfr[4];
#pragma unroll
    for (int i = 0; i < 2; i++)
      af[i] = *(const bf16x8v*)&As[(wm + i * 16 + mloc) * BK + quad * 8];
#pragma unroll
    for (int i = 0; i < 4; i++)
      bfr[i] = *(const bf16x8v*)&Bs[(wn + i * 16 + mloc) * BK + quad * 8];
#pragma unroll
    for (int mi = 0; mi < 2; mi++)
#pragma unroll
      for (int ni = 0; ni < 4; ni++)
        acc[mi][ni] = __builtin_amdgcn_mfma_f32_16x16x32_bf16(
            af[mi], bfr[ni], acc[mi][ni], 0, 0, 0);
    __syncthreads();
  }
#pragma unroll
  for (int ni = 0; ni < 4; ni++) {
    int col = n0 + wn + ni * 16 + mloc;
    float bv = bias[col];
#pragma unroll
    for (int mi = 0; mi < 2; mi++) {
      int rbase = m0 + wm + mi * 16 + quad * 4;
#pragma unroll
      for (int r = 0; r < 4; r++)
        H[(size_t)(rbase + r) * DIM + col] = (bf16_t)(acc[mi][ni][r] + bv);
    }
  }
}

// ---------------- kB: level means R2/R3/R4 + block scores + P softmax ----
__global__ __launch_bounds__(128) void kB_levels(
    const bf16_t* __restrict__ H, const float* __restrict__ mask01,
    const float* __restrict__ sw, const float* __restrict__ sbp,
    bf16_t* __restrict__ R2, bf16_t* __restrict__ R3, bf16_t* __restrict__ R4,
    float* __restrict__ P) {
  const int b = blockIdx.x, c = blockIdx.y;   // c: 0..170
  const int s0 = c * 12;
  const int t = threadIdx.x;
  const int d0 = t * 4;
  const float sb = sbp[0];

  f32x4 h[12];
  float ms[12], p[12];
  f32x4 swv = *(const f32x4*)(sw + d0);
#pragma unroll
  for (int i = 0; i < 12; i++) {
    int s = s0 + i;
    ms[i] = mask01[b * SP + s];
    if (s < SEQ) {
      h[i] = ldbf4(H + ((size_t)b * SEQ + s) * DIM + d0);
    } else {
      h[i].x = h[i].y = h[i].z = h[i].w = 0.f;
    }
    p[i] = h[i].x * swv.x + h[i].y * swv.y + h[i].z * swv.z + h[i].w * swv.w;
  }
#pragma unroll
  for (int j = 0; j < 6; j++) {
    int i0 = 2 * j;
    float cc = ms[i0] + ms[i0 + 1];
    f32x4 sm = h[i0] * ms[i0] + h[i0 + 1] * ms[i0 + 1];
    float sc = cc > 0.f ? 1.f / cc : 0.f;
    stbf4(R2 + ((size_t)b * NB2 + (c * 6 + j)) * DIM + d0, sm * sc);
  }
#pragma unroll
  for (int j = 0; j < 4; j++) {
    int i0 = 3 * j;
    float cc = ms[i0] + ms[i0 + 1] + ms[i0 + 2];
    f32x4 sm = h[i0] * ms[i0] + h[i0 + 1] * ms[i0 + 1] + h[i0 + 2] * ms[i0 + 2];
    float sc = cc > 0.f ? 1.f / cc : 0.f;
    stbf4(R3 + ((size_t)b * NB3 + (c * 4 + j)) * DIM + d0, sm * sc);
  }
#pragma unroll
  for (int j = 0; j < 3; j++) {
    int i0 = 4 * j;
    float cc = ms[i0] + ms[i0 + 1] + ms[i0 + 2] + ms[i0 + 3];
    f32x4 sm = h[i0] * ms[i0] + h[i0 + 1] * ms[i0 + 1] +
               h[i0 + 2] * ms[i0 + 2] + h[i0 + 3] * ms[i0 + 3];
    float sc = cc > 0.f ? 1.f / cc : 0.f;
    stbf4(R4 + ((size_t)b * NB4 + (c * 3 + j)) * DIM + d0, sm * sc);
  }
#pragma unroll
  for (int off = 32; off > 0; off >>= 1)
#pragma unroll
    for (int i = 0; i < 12; i++) p[i] += __shfl_down(p[i], off);
  __shared__ float hsw[2][12];
  int lane = t & 63, wv = t >> 6;
  if (lane == 0)
#pragma unroll
    for (int i = 0; i < 12; i++) hsw[wv][i] = p[i];
  __syncthreads();
#define HSUM(i) (hsw[0][i] + hsw[1][i])
  if (t < 12) {
    int i = t;
    float m1 = ms[i];
    float v1 = HSUM(i) * m1 + sb;
    int i2 = i & ~1;
    float cc2 = ms[i2] + ms[i2 + 1];
    float s2 = HSUM(i2) * ms[i2] + HSUM(i2 + 1) * ms[i2 + 1];
    float v2 = (cc2 > 0.f ? s2 / cc2 : 0.f) + sb;
    int i3 = (i >= 9) ? 9 : (i >= 6) ? 6 : (i >= 3) ? 3 : 0;
    float cc3 = ms[i3] + ms[i3 + 1] + ms[i3 + 2];
    float s3 = HSUM(i3) * ms[i3] + HSUM(i3 + 1) * ms[i3 + 1] +
               HSUM(i3 + 2) * ms[i3 + 2];
    float v3 = (cc3 > 0.f ? s3 / cc3 : 0.f) + sb;
    int i4 = i & ~3;
    float cc4 = ms[i4] + ms[i4 + 1] + ms[i4 + 2] + ms[i4 + 3];
    float s4 = HSUM(i4) * ms[i4] + HSUM(i4 + 1) * ms[i4 + 1] +
               HSUM(i4 + 2) * ms[i4 + 2] + HSUM(i4 + 3) * ms[i4 + 3];
    float v4 = (cc4 > 0.f ? s4 / cc4 : 0.f) + sb;
    const float NEG = -3.0e38f;
    float a1 = m1 > 0.f ? v1 : NEG, a2 = cc2 > 0.f ? v2 : NEG;
    float a3 = cc3 > 0.f ? v3 : NEG, a4 = cc4 > 0.f ? v4 : NEG;
    float mx = fmaxf(fmaxf(a1, a2), fmaxf(a3, a4));
    f32x4 o;
    if (mx <= NEG) {
      o.x = o.y = o.z = o.w = 0.25f;
    } else {
      float e1 = m1 > 0.f ? __expf(v1 - mx) : 0.f;
      float e2 = cc2 > 0.f ? __expf(v2 - mx) : 0.f;
      float e3 = cc3 > 0.f ? __expf(v3 - mx) : 0.f;
      float e4 = cc4 > 0.f ? __expf(v4 - mx) : 0.f;
      float inv = 1.f / (e1 + e2 + e3 + e4);
      o.x = e1 * inv; o.y = e2 * inv; o.z = e3 * inv; o.w = e4 * inv;
    }
    *(f32x4*)(P + ((size_t)b * SP + s0 + i) * 4) = o;
  }
#undef HSUM
}

// ---- k56: fused seq attention + output. Stages all of P[b] in LDS (SoA),
// one wave per output s-row does the full 2052-wide exp-dot + reduce, then
// the block combines reprs. No Wacc round-trip, no grid barrier.
__global__ __launch_bounds__(256) void k56_attn_out(
    const float* __restrict__ P, const float* __restrict__ mask01,
    const bf16_t* __restrict__ H, const bf16_t* __restrict__ R2,
    const bf16_t* __restrict__ R3, const bf16_t* __restrict__ R4,
    float* __restrict__ out, float* __restrict__ omask) {
  __shared__ float Px[SP], Py[SP], Pz[SP], Pw[SP];
  __shared__ f32x4 ws4[32];
  __shared__ float msk[32];
  __shared__ float c4w[4];
  const int b = blockIdx.x, lbase = blockIdx.y * 8;   // 8 l's per block
  const int t = threadIdx.x;
  const int w = t >> 6, lane = t & 63;

  // stage P[b] rows; zero masked rows (exp(0)=1, corrected via den -= nmask)
  float cnt0 = 0.f;
  for (int j = t; j < SP; j += 256) {
    f32x4 q = *(const f32x4*)(P + ((size_t)b * SP + j) * 4);
    float mf = mask01[b * SP + j];
    if (mf == 0.f) {
      q.x = q.y = q.z = q.w = 0.f;
      cnt0 += 1.f;
    }
    Px[j] = q.x; Py[j] = q.y; Pz[j] = q.z; Pw[j] = q.w;
  }
#pragma unroll
  for (int off = 32; off > 0; off >>= 1) cnt0 += __shfl_down(cnt0, off);
  if (lane == 0) c4w[w] = cnt0;
  __syncthreads();
  const float nmv = c4w[0] + c4w[1] + c4w[2] + c4w[3];

  // attention: wave w handles s-rows [lbase*4 + w*8, +8)
#pragma unroll 1
  for (int k = 0; k < 8; k++) {
    int sl = w * 8 + k;                    // 0..31 local s index
    int s = lbase * 4 + sl;
    float qx = Px[s], qy = Py[s], qz = Pz[s], qw = Pw[s];
    float ax = 0.f, ay = 0.f, az = 0.f, aw = 0.f, den = 0.f;
    for (int j = lane; j < SP; j += 64) {
      float px = Px[j], py = Py[j], pz = Pz[j], pw4 = Pw[j];
      float e = __expf(qx * px + qy * py + qz * pz + qw * pw4);
      den += e;
      ax += e * px; ay += e * py; az += e * pz; aw += e * pw4;
    }
#pragma unroll
    for (int off = 32; off > 0; off >>= 1) {
      ax += __shfl_down(ax, off); ay += __shfl_down(ay, off);
      az += __shfl_down(az, off); aw += __shfl_down(aw, off);
      den += __shfl_down(den, off);
    }
    if (lane == 0) {
      den -= nmv;
      float inv = den > 0.f ? 1.f / den : 0.f;
      f32x4 wv4; wv4.x = ax * inv; wv4.y = ay * inv;
      wv4.z = az * inv; wv4.w = aw * inv;
      ws4[sl] = wv4;
      msk[sl] = mask01[b * SP + s];
    }
  }
  __syncthreads();

  // output: 8 l's, 2 per pass (128 threads each)
#pragma unroll 1
  for (int p = 0; p < 4; p++) {
    int ll = p * 2 + (t >> 7);             // local l 0..7
    int l = lbase + ll;
    int d0 = (t & 127) * 4;
    f32x4 o; o.x = o.y = o.z = o.w = 0.f;
    float cnt = 0.f;
#pragma unroll
    for (int si = 0; si < 4; si++) {
      int sl = ll * 4 + si;
      int s = l * 4 + si;
      float m = msk[sl];
      f32x4 wv4 = ws4[sl];
      f32x4 r1 = ldbf4(H + ((size_t)b * SEQ + s) * DIM + d0);
      f32x4 r2 = ldbf4(R2 + ((size_t)b * NB2 + (s >> 1)) * DIM + d0);
      f32x4 r3 = ldbf4(R3 + ((size_t)b * NB3 + (s / 3)) * DIM + d0);
      f32x4 r4 = ldbf4(R4 + ((size_t)b * NB4 + (s >> 2)) * DIM + d0);
      o += m * (wv4.x * r1 + wv4.y * r2 + wv4.z * r3 + wv4.w * r4);
      cnt += m;
    }
    float inv = cnt > 0.f ? 1.f / cnt : 0.f;
    o *= inv;
    *(f32x4*)(out + ((size_t)b * NL + l) * DIM + d0) = o;
    if ((t & 127) == 0) omask[b * NL + l] = cnt > 0.f ? 1.f : 0.f;
  }
}

// ---------------- launch ----------------
extern "C" void kernel_launch(void* const* d_in, const int* in_sizes, int n_in,
                              void* d_out, int out_size, void* d_ws, size_t ws_size,
                              hipStream_t stream) {
  const int*   x    = (const int*)d_in[0];
  const void*  mraw = d_in[1];
  const float* emb  = (const float*)d_in[2];
  const float* dww  = (const float*)d_in[3];
  const float* dwb  = (const float*)d_in[4];
  const float* pw   = (const float*)d_in[5];
  const float* pwb  = (const float*)d_in[6];
  const float* sw   = (const float*)d_in[7];
  const float* sb   = (const float*)d_in[8];

  char* ws = (char*)d_ws;
  size_t off = 0;
  auto alloc = [&](size_t bytes) {
    size_t o = off;
    off = (off + bytes + 255) & ~(size_t)255;
    return o;
  };
  bf16_t* A    = (bf16_t*)(ws + alloc((size_t)NBATCH * SEQ * DIM * 2));
  bf16_t* H    = (bf16_t*)(ws + alloc((size_t)NBATCH * SEQ * DIM * 2));
  bf16_t* Wt   = (bf16_t*)(ws + alloc((size_t)DIM * DIM * 2));
  bf16_t* R2   = (bf16_t*)(ws + alloc((size_t)NBATCH * NB2 * DIM * 2));
  bf16_t* R3   = (bf16_t*)(ws + alloc((size_t)NBATCH * NB3 * DIM * 2));
  bf16_t* R4   = (bf16_t*)(ws + alloc((size_t)NBATCH * NB4 * DIM * 2));
  float* mask01 = (float*)(ws + alloc((size_t)NBATCH * SP * 4));
  float* P     = (float*)(ws + alloc((size_t)NBATCH * SP * 4 * 4));

  float* out   = (float*)d_out;
  float* omask = out + (size_t)NBATCH * NL * DIM;

  kA_prep<<<GA_WT + GA_MASK + GA_A, 256, 0, stream>>>(pw, Wt, mraw, mask01,
                                                      x, emb, dww, dwb, A);
  k2_gemm<<<1024, 256, 0, stream>>>(A, Wt, pwb, H);
  kB_levels<<<dim3(NBATCH, 171), 128, 0, stream>>>(H, mask01, sw, sb,
                                                   R2, R3, R4, P);
  k56_attn_out<<<dim3(NBATCH, 64), 256, 0, stream>>>(P, mask01, H, R2, R3, R4,
                                                     out, omask);
}